// Round 1
// baseline (478.226 us; speedup 1.0000x reference)
//
#include <hip/hip_runtime.h>
#include <hip/hip_bf16.h>
#include <math.h>

#define Bv 4
#define Pv 1536
#define Mv 4
#define DPHIv 32
#define DINv 128
#define Kv 20
#define Sv 100
#define TT 4
#define NTB ((Pv - 1 + TT - 1) / TT)   // 384

__device__ __forceinline__ float fast_tanh(float x) {
  // tanh(x) = 1 - 2/(exp(2x)+1); saturates correctly for |x| large
  float e = __expf(2.0f * x);
  return 1.0f - 2.0f / (e + 1.0f);
}
__device__ __forceinline__ float gelu_f(float x) {
  const float c = 0.7978845608028654f; // sqrt(2/pi)
  float t = fast_tanh(c * (x + 0.044715f * x * x * x));
  return 0.5f * x * (1.0f + t);
}
__device__ __forceinline__ float softplus1(float y) {
  // stable: max(y,0) + log1p(exp(-|y|)) — matches jax.nn.softplus
  return fmaxf(y, 0.0f) + log1pf(__expf(-fabsf(y)));
}
__device__ __forceinline__ float softplus10(float x) {
  float y = 10.0f * x;
  return (fmaxf(y, 0.0f) + log1pf(__expf(-fabsf(y)))) * 0.1f;
}

// ---------------------------------------------------------------------------
// Kernel 1: cumulative-softmax attention -> embed (B,P,DIN) fp32 in workspace.
// out5[p,m,d] = (sum_{q<=p} e_q v[q,d]) / (sum_{q<=p} e_q), e_q = exp(pre-GM);
// the exp(-cummax) factor of the reference cancels in the ratio.
// One block per (b,m); sequential scan with LDS-staged values chunks.
// ---------------------------------------------------------------------------
__global__ __launch_bounds__(64) void attn_kernel(
    const float* __restrict__ values,   // (B,P,DPHI)
    const float* __restrict__ pre,      // (B,P,M)
    const float* __restrict__ mask,     // (B,P)
    float* __restrict__ emb)            // (B,P,DIN)
{
  const int b = blockIdx.x >> 2;
  const int m = blockIdx.x & 3;
  const int tid = threadIdx.x;
  const int CH = 256;

  __shared__ float s_e[Pv];
  __shared__ float s_mk[Pv];
  __shared__ float s_v[CH * DPHIv];   // 32 KB chunk of values

  // global max over p of pre[b,:,m]
  float mx = -1e30f;
  for (int p = tid; p < Pv; p += 64) mx = fmaxf(mx, pre[(b * Pv + p) * Mv + m]);
#pragma unroll
  for (int o = 32; o > 0; o >>= 1) mx = fmaxf(mx, __shfl_xor(mx, o));

  for (int p = tid; p < Pv; p += 64) {
    s_e[p] = __expf(pre[(b * Pv + p) * Mv + m] - mx);
    s_mk[p] = mask[b * Pv + p];
  }
  __syncthreads();

  float acc = 0.f, accE = 0.f;
  for (int c = 0; c < Pv; c += CH) {
    for (int i = tid; i < CH * DPHIv; i += 64)
      s_v[i] = values[(b * Pv + c) * DPHIv + i];
    __syncthreads();
    if (tid < DPHIv) {
      for (int q = 0; q < CH; ++q) {
        float e = s_e[c + q];
        accE += e;
        acc = fmaf(e, s_v[q * DPHIv + tid], acc);
        emb[(b * Pv + c + q) * DINv + m * DPHIv + tid] =
            __fdividef(acc, accE) * s_mk[c + q];
      }
    }
    __syncthreads();
  }
}

// ---------------------------------------------------------------------------
// Kernel 2: per block = 4 consecutive t's of one batch.
//  - 3 matvecs (embed @ W_{start,conv,dec}) + activations + mask
//  - log path: cell_t dot W_int[:,ktype] (single column)
//  - integral path: cell_tau[128][100] staged in LDS, then 200 threads do
//    (s, k-half) dot products, softplus, reduce; atomics into out (B,2).
// ---------------------------------------------------------------------------
__global__ __launch_bounds__(256) void main_kernel(
    const float* __restrict__ emb,      // (B,P,DIN)
    const float* __restrict__ mask,     // (B,P)
    const float* __restrict__ times,    // (B,P)
    const float* __restrict__ taus_u,   // (B,P-1,1,S)
    const int* __restrict__ types,      // (B,P)
    const float* __restrict__ W_start, const float* __restrict__ b_start,
    const float* __restrict__ W_conv,  const float* __restrict__ b_conv,
    const float* __restrict__ W_dec,   const float* __restrict__ b_dec,
    const float* __restrict__ W_int,   const float* __restrict__ b_int,
    float* __restrict__ out)            // (B,2), pre-zeroed
{
  const int tid = threadIdx.x;
  const int b = blockIdx.x / NTB;
  const int t0 = (blockIdx.x % NTB) * TT;

  __shared__ float s_emb[TT][DINv];
  __shared__ float s_start[TT][DINv];
  __shared__ float s_conv[TT][DINv];
  __shared__ float s_omega[TT][DINv];
  __shared__ float s_W[2][DINv][12];        // W_int split in k-halves, padded rows
  __shared__ float s_tau[TT][Sv];
  __shared__ float s_ct[DINv][Sv + 4];      // [d][s], pad 104 -> conflict-free
  __shared__ float s_dt[TT], s_npm[TT];
  __shared__ int   s_kt[TT];
  __shared__ float s_bint[Kv];
  __shared__ float s_red[8];

  // stage W_int (DIN,K) -> s_W[kh][d][kk]
  for (int i = tid; i < DINv * Kv; i += 256) {
    int d = i / Kv, k = i % Kv;
    s_W[k / 10][d][k % 10] = W_int[i];
  }
  if (tid < Kv) s_bint[tid] = b_int[tid];

  for (int i = tid; i < TT * DINv; i += 256) {
    int r = i >> 7, d = i & 127;
    int t = t0 + r;
    s_emb[r][d] = (t < Pv - 1) ? emb[(b * Pv + t) * DINv + d] : 0.f;
  }
  for (int i = tid; i < TT * Sv; i += 256) {
    int r = i / Sv, s = i % Sv;
    int t = t0 + r;
    s_tau[r][s] = (t < Pv - 1) ? taus_u[(b * (Pv - 1) + t) * Sv + s] : 0.f;
  }
  if (tid < TT) {
    int t = t0 + tid;
    float np = 0.f, dtv = 0.f; int kt = 0;
    if (t < Pv - 1) {
      np = mask[b * Pv + t + 1];
      dtv = (times[b * Pv + t + 1] - times[b * Pv + t]) * np;
      int ty = types[b * Pv + t + 1] - 1;   // types in 1..K -> 0..K-1
      kt = min(max(ty, 0), Kv - 1);
    }
    s_npm[tid] = np; s_dt[tid] = dtv; s_kt[tid] = kt;
  }
  __syncthreads();

  // ---- matvecs: out[r][j] = sum_d emb[r][d] * W[d][j]  (W column j per thread)
  {
    const int j = tid & 127;
    const int half = tid >> 7;
    for (int round = 0; round < 2; ++round) {
      int which = round * 2 + half;   // 0:start 1:conv 2:dec 3:idle
      if (which < 3) {
        const float* W = (which == 0) ? W_start : (which == 1) ? W_conv : W_dec;
        const float* bias = (which == 0) ? b_start : (which == 1) ? b_conv : b_dec;
        float acc[TT];
#pragma unroll
        for (int r = 0; r < TT; ++r) acc[r] = 0.f;
        for (int d = 0; d < DINv; ++d) {
          float w = W[d * DINv + j];
#pragma unroll
          for (int r = 0; r < TT; ++r) acc[r] = fmaf(s_emb[r][d], w, acc[r]);
        }
        float bj = bias[j];
#pragma unroll
        for (int r = 0; r < TT; ++r) {
          float v = acc[r] + bj;
          float np = s_npm[r];
          if (which == 0)      s_start[r][j] = gelu_f(v) * np;
          else if (which == 1) s_conv[r][j]  = gelu_f(v) * np;
          else                 s_omega[r][j] = softplus10(v) * np;
        }
      }
    }
  }
  __syncthreads();

  float logsum_local = 0.f, integ_local = 0.f;
  const int nr = min(TT, (Pv - 1) - t0);
  for (int r = 0; r < nr; ++r) {
    const float dtv = s_dt[r];

    // ---- log path: cell_t element + partial of dot with W_int[:,ktype]
    float pl = 0.f;
    if (tid < DINv) {
      float cv = s_conv[r][tid];
      float dl = s_start[r][tid] - cv;
      float om = s_omega[r][tid];
      float ct = fast_tanh(cv + dl * __expf(-om * dtv));
      int kq = s_kt[r];
      pl = ct * s_W[kq / 10][tid][kq % 10];
    }

    // ---- phase A: cell_tau[d][s] into LDS (50 elems/thread)
#pragma unroll 2
    for (int i = 0; i < (DINv * Sv) / 256; ++i) {
      int lin = i * 256 + tid;
      int s = lin % Sv;
      int d = lin / Sv;
      float cv = s_conv[r][d];
      float dl = s_start[r][d] - cv;
      float om = s_omega[r][d];
      float ex = __expf(-om * dtv * s_tau[r][s]);
      s_ct[d][s] = fast_tanh(cv + dl * ex);
    }
    __syncthreads();

    // ---- phase B: (s, k-half) dot products + softplus + k-sum
    float pc = 0.f;
    if (tid < 2 * Sv) {
      int s = tid >> 1, kh = tid & 1;
      float acc[10];
#pragma unroll
      for (int kk = 0; kk < 10; ++kk) acc[kk] = 0.f;
#pragma unroll 2
      for (int d = 0; d < DINv; ++d) {
        float c = s_ct[d][s];
#pragma unroll
        for (int kk = 0; kk < 10; ++kk)
          acc[kk] = fmaf(c, s_W[kh][d][kk], acc[kk]);
      }
      float sums = 0.f;
#pragma unroll
      for (int kk = 0; kk < 10; ++kk)
        sums += softplus1(acc[kk] + s_bint[kh * 10 + kk]);
      sums += __shfl_xor(sums, 1);   // combine the two k-halves (pair lanes)
      pc = kh ? 0.f : sums;
    }

    // ---- joint block reduce of (log-dot, integral-sum)
    float v0 = pl, v1 = pc;
#pragma unroll
    for (int o = 32; o > 0; o >>= 1) {
      v0 += __shfl_xor(v0, o);
      v1 += __shfl_xor(v1, o);
    }
    int wv = tid >> 6;
    if ((tid & 63) == 0) { s_red[wv * 2] = v0; s_red[wv * 2 + 1] = v1; }
    __syncthreads();
    if (tid == 0) {
      float dot = 0.f, tot = 0.f;
#pragma unroll
      for (int w = 0; w < 4; ++w) { dot += s_red[w * 2]; tot += s_red[w * 2 + 1]; }
      int kq = s_kt[r];
      float sk = softplus1(dot + s_bint[kq]);
      if (s_npm[r] > 0.f) logsum_local += logf(sk);
      integ_local += dtv * tot * (1.0f / Sv);
    }
    __syncthreads();   // protect s_ct / s_red for next r
  }

  if (tid == 0) {
    atomicAdd(&out[b * 2 + 0], logsum_local);
    atomicAdd(&out[b * 2 + 1], integ_local);
  }
}

extern "C" void kernel_launch(void* const* d_in, const int* in_sizes, int n_in,
                              void* d_out, int out_size, void* d_ws, size_t ws_size,
                              hipStream_t stream) {
  const float* values  = (const float*)d_in[0];
  const float* pre     = (const float*)d_in[1];
  const float* mask    = (const float*)d_in[2];
  const float* times   = (const float*)d_in[3];
  const float* tausu   = (const float*)d_in[4];
  const int*   types   = (const int*)d_in[5];
  const float* W_start = (const float*)d_in[6];
  const float* b_start = (const float*)d_in[7];
  const float* W_conv  = (const float*)d_in[8];
  const float* b_conv  = (const float*)d_in[9];
  const float* W_dec   = (const float*)d_in[10];
  const float* b_dec   = (const float*)d_in[11];
  const float* W_int   = (const float*)d_in[12];
  const float* b_int   = (const float*)d_in[13];
  float* out = (float*)d_out;
  float* emb = (float*)d_ws;   // B*P*DIN floats = 3.1 MB

  hipMemsetAsync(out, 0, out_size * sizeof(float), stream);
  attn_kernel<<<dim3(Bv * Mv), dim3(64), 0, stream>>>(values, pre, mask, emb);
  main_kernel<<<dim3(Bv * NTB), dim3(256), 0, stream>>>(
      emb, mask, times, tausu, types,
      W_start, b_start, W_conv, b_conv, W_dec, b_dec, W_int, b_int, out);
}

// Round 6
// 322.462 us; speedup vs baseline: 1.4830x; 1.4830x over previous
//
#include <hip/hip_runtime.h>
#include <hip/hip_bf16.h>
#include <math.h>

#define Bv 4
#define Pv 1536
#define Mv 4
#define DPHIv 32
#define DINv 128
#define Kv 20
#define Sv 100
#define TT 4
#define NTB ((Pv - 1 + TT - 1) / TT)   // 384
#define ACH 256                         // attn chunk
#define NCH (Pv / ACH)                  // 6

typedef short bf16x8 __attribute__((ext_vector_type(8)));
typedef float f32x4 __attribute__((ext_vector_type(4)));

__device__ __forceinline__ float fast_tanh(float x) {
  // tanh(x) = 1 - 2/(exp(2x)+1); saturates correctly for |x| large
  float e = __expf(2.0f * x);
  return 1.0f - __fdividef(2.0f, e + 1.0f);
}
__device__ __forceinline__ float gelu_f(float x) {
  const float c = 0.7978845608028654f;
  float t = fast_tanh(c * (x + 0.044715f * x * x * x));
  return 0.5f * x * (1.0f + t);
}
__device__ __forceinline__ float softplus1(float y) {
  return fmaxf(y, 0.0f) + log1pf(__expf(-fabsf(y)));
}
__device__ __forceinline__ float softplus10(float x) {
  float y = 10.0f * x;
  return (fmaxf(y, 0.0f) + log1pf(__expf(-fabsf(y)))) * 0.1f;
}

// swizzled halfword address within a [rows][128] bf16 tile (16B-unit XOR)
__device__ __forceinline__ int swz(int row, int d) {
  return row * 128 + ((((d >> 3) ^ row) & 7) << 3) + ((d >> 6) << 6) + (d & 7);
}

// ---------------------------------------------------------------------------
// Attention as prefix-scan over chunks: block = (b, m, chunk of 256).
// e_q = exp(pre - local_max); out[p] = (sum_{q<=p} e v)/(sum e) * mask.
// The exp(-cummax) of the reference cancels in the ratio.
// ---------------------------------------------------------------------------
__global__ __launch_bounds__(256) void attn_kernel(
    const float* __restrict__ values,   // (B,P,DPHI)
    const float* __restrict__ pre,      // (B,P,M)
    const float* __restrict__ mask,     // (B,P)
    float* __restrict__ emb)            // (B,P,DIN)
{
  const int c = blockIdx.x % NCH;
  const int bm = blockIdx.x / NCH;
  const int b = bm >> 2;
  const int m = bm & 3;
  const int tid = threadIdx.x;
  const int end = (c + 1) * ACH;
  const int hb = c * ACH;

  __shared__ float s_e[Pv];
  __shared__ float s_v[ACH * DPHIv];
  __shared__ float s_mk[ACH];
  __shared__ float s_H[8][DPHIv];
  __shared__ float s_HE[8];
  __shared__ float s_mx[4];

  float mx = -1e30f;
  for (int p = tid; p < end; p += 256) mx = fmaxf(mx, pre[(b * Pv + p) * Mv + m]);
#pragma unroll
  for (int o = 32; o > 0; o >>= 1) mx = fmaxf(mx, __shfl_xor(mx, o));
  if ((tid & 63) == 0) s_mx[tid >> 6] = mx;
  __syncthreads();
  mx = fmaxf(fmaxf(s_mx[0], s_mx[1]), fmaxf(s_mx[2], s_mx[3]));

  for (int p = tid; p < end; p += 256)
    s_e[p] = __expf(pre[(b * Pv + p) * Mv + m] - mx);
  for (int i = tid; i < ACH * DPHIv; i += 256)
    s_v[i] = values[(b * Pv + hb) * DPHIv + i];
  if (tid < ACH) s_mk[tid] = mask[b * Pv + hb + tid];
  __syncthreads();

  // head partial sums (q < hb), 8 groups x 32 d-lanes
  {
    const int g = tid >> 5, d = tid & 31;
    const int per = hb >> 3;
    float acc = 0.f, accE = 0.f;
    for (int p = g * per; p < (g + 1) * per; ++p) {
      float e = s_e[p];
      accE += e;
      acc = fmaf(e, values[(b * Pv + p) * DPHIv + d], acc);
    }
    s_H[g][d] = acc;
    if (d == 0) s_HE[g] = accE;
  }
  __syncthreads();

  if (tid < DPHIv) {
    float a = 0.f, aE = 0.f;
#pragma unroll
    for (int g = 0; g < 8; ++g) { a += s_H[g][tid]; aE += s_HE[g]; }
    for (int q = 0; q < ACH; ++q) {
      float e = s_e[hb + q];
      aE += e;
      a = fmaf(e, s_v[q * DPHIv + tid], a);
      emb[(b * Pv + hb + q) * DINv + m * DPHIv + tid] =
          __fdividef(a, aE) * s_mk[q];
    }
  }
}

// ---------------------------------------------------------------------------
// Main kernel: block = 4 consecutive t's of one batch.
// matvecs (VALU) -> per t: phase A builds cell_tau as bf16 hi/lo in LDS,
// phase B does the 100x128x20 GEMM on MFMA (bf16 hi/lo split = fp32 grade),
// softplus epilogue + joint block reduce.
// ---------------------------------------------------------------------------
__global__ __launch_bounds__(256, 2) void main_kernel(
    const float* __restrict__ emb,      // (B,P,DIN)
    const float* __restrict__ mask,     // (B,P)
    const float* __restrict__ times,    // (B,P)
    const float* __restrict__ taus_u,   // (B,P-1,1,S)
    const int* __restrict__ types,      // (B,P)
    const float* __restrict__ W_start, const float* __restrict__ b_start,
    const float* __restrict__ W_conv,  const float* __restrict__ b_conv,
    const float* __restrict__ W_dec,   const float* __restrict__ b_dec,
    const float* __restrict__ W_int,   const float* __restrict__ b_int,
    float* __restrict__ out)            // (B,2), pre-zeroed
{
  const int tid = threadIdx.x;
  const int b = blockIdx.x / NTB;
  const int t0 = (blockIdx.x % NTB) * TT;
  const int lane = tid & 63;
  const int wv = tid >> 6;

  __shared__ float s_emb[TT][DINv];
  __shared__ float s_start[TT][DINv];
  __shared__ float s_conv[TT][DINv];
  __shared__ float s_omega[TT][DINv];
  __shared__ float s_tau[TT][Sv];
  __shared__ __align__(16) short s_cthi[Sv * DINv];   // [s][d] swizzled, bf16 hi
  __shared__ __align__(16) short s_ctlo[Sv * DINv];   // bf16 lo
  __shared__ __align__(16) short s_wthi[32 * DINv];   // [k][d] swizzled (k>=20 zero)
  __shared__ __align__(16) short s_wtlo[32 * DINv];
  __shared__ float s_dt[TT], s_npm[TT];
  __shared__ int   s_kt[TT];
  __shared__ float s_bint[Kv];
  __shared__ float s_red[8];

  // ---- one-time staging -------------------------------------------------
  for (int i = tid; i < 32 * DINv; i += 256) {
    int k = i >> 7, d = i & 127;
    float w = (k < Kv) ? W_int[d * Kv + k] : 0.f;
    __hip_bfloat16 h = __float2bfloat16(w);
    float hf = __bfloat162float(h);
    __hip_bfloat16 l = __float2bfloat16(w - hf);
    int a = swz(k, d);
    s_wthi[a] = *(short*)&h;
    s_wtlo[a] = *(short*)&l;
  }
  if (tid < Kv) s_bint[tid] = b_int[tid];

  for (int i = tid; i < TT * DINv; i += 256) {
    int r = i >> 7, d = i & 127;
    int t = t0 + r;
    s_emb[r][d] = (t < Pv - 1) ? emb[(b * Pv + t) * DINv + d] : 0.f;
  }
  for (int i = tid; i < TT * Sv; i += 256) {
    int r = i / Sv, s = i % Sv;
    int t = t0 + r;
    s_tau[r][s] = (t < Pv - 1) ? taus_u[(b * (Pv - 1) + t) * Sv + s] : 0.f;
  }
  if (tid < TT) {
    int t = t0 + tid;
    float np = 0.f, dtv = 0.f; int kt = 0;
    if (t < Pv - 1) {
      np = mask[b * Pv + t + 1];
      dtv = (times[b * Pv + t + 1] - times[b * Pv + t]) * np;
      int ty = types[b * Pv + t + 1] - 1;
      kt = min(max(ty, 0), Kv - 1);
    }
    s_npm[tid] = np; s_dt[tid] = dtv; s_kt[tid] = kt;
  }
  __syncthreads();

  // ---- matvecs ----------------------------------------------------------
  {
    const int j = tid & 127;
    const int half = tid >> 7;
    for (int round = 0; round < 2; ++round) {
      int which = round * 2 + half;   // 0:start 1:conv 2:dec 3:idle
      if (which < 3) {
        const float* W = (which == 0) ? W_start : (which == 1) ? W_conv : W_dec;
        const float* bias = (which == 0) ? b_start : (which == 1) ? b_conv : b_dec;
        float acc[TT];
#pragma unroll
        for (int r = 0; r < TT; ++r) acc[r] = 0.f;
        for (int d = 0; d < DINv; ++d) {
          float w = W[d * DINv + j];
#pragma unroll
          for (int r = 0; r < TT; ++r) acc[r] = fmaf(s_emb[r][d], w, acc[r]);
        }
        float bj = bias[j];
#pragma unroll
        for (int r = 0; r < TT; ++r) {
          float v = acc[r] + bj;
          float np = s_npm[r];
          if (which == 0)      s_start[r][j] = gelu_f(v) * np;
          else if (which == 1) s_conv[r][j]  = gelu_f(v) * np;
          else                 s_omega[r][j] = softplus10(v) * np;
        }
      }
    }
  }
  __syncthreads();

  float logsum_local = 0.f, integ_local = 0.f;
  const int nr = min(TT, (Pv - 1) - t0);

  // MFMA tile plan: 7 M-tiles x 2 N-tiles; wave wv owns nt = wv&1,
  // mt = (wv>>1) + 2u for u=0..3 (mt<7).
  const int nt = wv & 1;
  const int mt0 = wv >> 1;
  const int colk = nt * 16 + (lane & 15);
  const float bk = (colk < Kv) ? s_bint[colk] : 0.f;

  for (int r = 0; r < nr; ++r) {
    const float dtv = s_dt[r];

    // ---- log path partial: cell_t[d] * W_int[d][ktype]
    float pl = 0.f;
    if (tid < DINv) {
      float cv = s_conv[r][tid];
      float dl = s_start[r][tid] - cv;
      float om = s_omega[r][tid];
      float ct = fast_tanh(fmaf(dl, __expf(-om * dtv), cv));
      pl = ct * W_int[tid * Kv + s_kt[r]];
    }

    // ---- phase A: cell_tau -> bf16 hi/lo in LDS (thread owns fixed d)
    {
      const int d = tid & 127;
      const int sh = tid >> 7;
      float cv = s_conv[r][d];
      float dl = s_start[r][d] - cv;
      float om = s_omega[r][d];
      float a1 = -om * dtv;
#pragma unroll 2
      for (int ii = 0; ii < Sv / 2; ++ii) {
        int s = 2 * ii + sh;
        float ex = __expf(a1 * s_tau[r][s]);
        float x = fmaf(dl, ex, cv);
        float e2 = __expf(2.0f * x);
        float ct = 1.0f - __fdividef(2.0f, e2 + 1.0f);
        __hip_bfloat16 h = __float2bfloat16(ct);
        float hf = __bfloat162float(h);
        __hip_bfloat16 lo = __float2bfloat16(ct - hf);
        int a = swz(s, d);
        s_cthi[a] = *(short*)&h;
        s_ctlo[a] = *(short*)&lo;
      }
    }
    __syncthreads();

    // ---- phase B: C[s][k] = ct[s][:] @ W[:,k] via bf16 hi/lo MFMA
    float psum = 0.f;
    {
      f32x4 a0 = {0.f,0.f,0.f,0.f}, a1 = {0.f,0.f,0.f,0.f};
      f32x4 a2 = {0.f,0.f,0.f,0.f}, a3 = {0.f,0.f,0.f,0.f};
#pragma unroll
      for (int ks = 0; ks < 4; ++ks) {
        const int ub = (ks * 4 + (lane >> 4)) << 3;   // d-base for this lane
        const int baddr = colk * 128 + ((((ub >> 3) ^ colk) & 7) << 3) + ((ub >> 6) << 6);
        bf16x8 bh = *(const bf16x8*)&s_wthi[baddr];
        bf16x8 bl = *(const bf16x8*)&s_wtlo[baddr];
#pragma unroll
        for (int u = 0; u < 4; ++u) {
          int mt = mt0 + 2 * u;
          if (mt < 7) {
            int sr = min(mt * 16 + (lane & 15), Sv - 1);
            int aaddr = sr * 128 + ((((ub >> 3) ^ sr) & 7) << 3) + ((ub >> 6) << 6);
            bf16x8 ah = *(const bf16x8*)&s_cthi[aaddr];
            bf16x8 al = *(const bf16x8*)&s_ctlo[aaddr];
            f32x4 acc = (u == 0) ? a0 : (u == 1) ? a1 : (u == 2) ? a2 : a3;
            acc = __builtin_amdgcn_mfma_f32_16x16x32_bf16(ah, bh, acc, 0, 0, 0);
            acc = __builtin_amdgcn_mfma_f32_16x16x32_bf16(al, bh, acc, 0, 0, 0);
            acc = __builtin_amdgcn_mfma_f32_16x16x32_bf16(ah, bl, acc, 0, 0, 0);
            if (u == 0) a0 = acc; else if (u == 1) a1 = acc; else if (u == 2) a2 = acc; else a3 = acc;
          }
        }
      }
      // epilogue: softplus + sum (C layout: col=lane&15, row=(lane>>4)*4+j)
      if (colk < Kv) {
#pragma unroll
        for (int u = 0; u < 4; ++u) {
          int mt = mt0 + 2 * u;
          if (mt < 7) {
            f32x4 acc = (u == 0) ? a0 : (u == 1) ? a1 : (u == 2) ? a2 : a3;
#pragma unroll
            for (int j = 0; j < 4; ++j) {
              int s = mt * 16 + ((lane >> 4) << 2) + j;
              if (s < Sv) psum += softplus1(acc[j] + bk);
            }
          }
        }
      }
    }

    // ---- joint block reduce (log dot, integral sum)
    float v0 = pl, v1 = psum;
#pragma unroll
    for (int o = 32; o > 0; o >>= 1) {
      v0 += __shfl_xor(v0, o);
      v1 += __shfl_xor(v1, o);
    }
    if ((tid & 63) == 0) { s_red[wv * 2] = v0; s_red[wv * 2 + 1] = v1; }
    __syncthreads();
    if (tid == 0) {
      float dot = 0.f, tot = 0.f;
#pragma unroll
      for (int w = 0; w < 4; ++w) { dot += s_red[w * 2]; tot += s_red[w * 2 + 1]; }
      float sk = softplus1(dot + s_bint[s_kt[r]]);
      if (s_npm[r] > 0.f) logsum_local += logf(sk);
      integ_local += dtv * tot * (1.0f / Sv);
    }
    __syncthreads();   // protect s_ct* / s_red for next r
  }

  if (tid == 0) {
    atomicAdd(&out[b * 2 + 0], logsum_local);
    atomicAdd(&out[b * 2 + 1], integ_local);
  }
}

extern "C" void kernel_launch(void* const* d_in, const int* in_sizes, int n_in,
                              void* d_out, int out_size, void* d_ws, size_t ws_size,
                              hipStream_t stream) {
  const float* values  = (const float*)d_in[0];
  const float* pre     = (const float*)d_in[1];
  const float* mask    = (const float*)d_in[2];
  const float* times   = (const float*)d_in[3];
  const float* tausu   = (const float*)d_in[4];
  const int*   types   = (const int*)d_in[5];
  const float* W_start = (const float*)d_in[6];
  const float* b_start = (const float*)d_in[7];
  const float* W_conv  = (const float*)d_in[8];
  const float* b_conv  = (const float*)d_in[9];
  const float* W_dec   = (const float*)d_in[10];
  const float* b_dec   = (const float*)d_in[11];
  const float* W_int   = (const float*)d_in[12];
  const float* b_int   = (const float*)d_in[13];
  float* out = (float*)d_out;
  float* emb = (float*)d_ws;   // B*P*DIN floats = 3.1 MB

  (void)hipMemsetAsync(out, 0, out_size * sizeof(float), stream);
  attn_kernel<<<dim3(Bv * Mv * NCH), dim3(256), 0, stream>>>(values, pre, mask, emb);
  main_kernel<<<dim3(Bv * NTB), dim3(256), 0, stream>>>(
      emb, mask, times, tausu, types,
      W_start, b_start, W_conv, b_conv, W_dec, b_dec, W_int, b_int, out);
}

// Round 9
// 283.970 us; speedup vs baseline: 1.6841x; 1.1355x over previous
//
#include <hip/hip_runtime.h>
#include <hip/hip_bf16.h>
#include <math.h>

#define Bv 4
#define Pv 1536
#define Mv 4
#define DPHIv 32
#define DINv 128
#define Kv 20
#define Sv 100
#define TT 4
#define NTB ((Pv - 1 + TT - 1) / TT)   // 384
#define ACH 128                         // attn chunk
#define NCH (Pv / ACH)                  // 12

typedef short bf16x8 __attribute__((ext_vector_type(8)));
typedef float f32x4 __attribute__((ext_vector_type(4)));
typedef unsigned int u32;
typedef u32 u32x4 __attribute__((ext_vector_type(4)));

__device__ __forceinline__ float fast_tanh(float x) {
  float e = __expf(2.0f * x);
  return 1.0f - __fdividef(2.0f, e + 1.0f);
}
__device__ __forceinline__ float gelu_f(float x) {
  const float c = 0.7978845608028654f;
  float t = fast_tanh(c * (x + 0.044715f * x * x * x));
  return 0.5f * x * (1.0f + t);
}
__device__ __forceinline__ float softplus1(float y) {
  return fmaxf(y, 0.0f) + log1pf(__expf(-fabsf(y)));
}
__device__ __forceinline__ float softplus10(float x) {
  float y = 10.0f * x;
  return (fmaxf(y, 0.0f) + log1pf(__expf(-fabsf(y)))) * 0.1f;
}

// ---------------------------------------------------------------------------
// Attention as prefix-scan over chunks: block = (b, m, chunk of 128).
// ---------------------------------------------------------------------------
__global__ __launch_bounds__(256) void attn_kernel(
    const float* __restrict__ values,   // (B,P,DPHI)
    const float* __restrict__ pre,      // (B,P,M)
    const float* __restrict__ mask,     // (B,P)
    float* __restrict__ emb)            // (B,P,DIN)
{
  const int c = blockIdx.x % NCH;
  const int bm = blockIdx.x / NCH;
  const int b = bm >> 2;
  const int m = bm & 3;
  const int tid = threadIdx.x;
  const int end = (c + 1) * ACH;
  const int hb = c * ACH;

  __shared__ float s_e[Pv];
  __shared__ float s_v[ACH * DPHIv];
  __shared__ float s_mk[ACH];
  __shared__ float s_H[8][DPHIv];
  __shared__ float s_HE[8];
  __shared__ float s_mx[4];

  float mx = -1e30f;
  for (int p = tid; p < end; p += 256) mx = fmaxf(mx, pre[(b * Pv + p) * Mv + m]);
#pragma unroll
  for (int o = 32; o > 0; o >>= 1) mx = fmaxf(mx, __shfl_xor(mx, o));
  if ((tid & 63) == 0) s_mx[tid >> 6] = mx;
  __syncthreads();
  mx = fmaxf(fmaxf(s_mx[0], s_mx[1]), fmaxf(s_mx[2], s_mx[3]));

  for (int p = tid; p < end; p += 256)
    s_e[p] = __expf(pre[(b * Pv + p) * Mv + m] - mx);
  for (int i = tid; i < ACH * DPHIv; i += 256)
    s_v[i] = values[(b * Pv + hb) * DPHIv + i];
  if (tid < ACH) s_mk[tid] = mask[b * Pv + hb + tid];
  __syncthreads();

  // head partial sums (q < hb), 8 groups x 32 d-lanes
  {
    const int g = tid >> 5, d = tid & 31;
    const int per = hb >> 3;
    float acc = 0.f, accE = 0.f;
    for (int p = g * per; p < (g + 1) * per; ++p) {
      float e = s_e[p];
      accE += e;
      acc = fmaf(e, values[(b * Pv + p) * DPHIv + d], acc);
    }
    s_H[g][d] = acc;
    if (d == 0) s_HE[g] = accE;
  }
  __syncthreads();

  if (tid < DPHIv) {
    float a = 0.f, aE = 0.f;
#pragma unroll
    for (int g = 0; g < 8; ++g) { a += s_H[g][tid]; aE += s_HE[g]; }
    for (int q = 0; q < ACH; ++q) {
      float e = s_e[hb + q];
      aE += e;
      a = fmaf(e, s_v[q * DPHIv + tid], a);
      emb[(b * Pv + hb + q) * DINv + m * DPHIv + tid] =
          __fdividef(a, aE) * s_mk[q];
    }
  }
}

// ---------------------------------------------------------------------------
// Main kernel: block = 4 consecutive t's of one batch, 4 waves.
// Wave wv owns M-tiles {wv, wv+4} (7 tiles cover s=0..99, padded to 112) and
// BOTH 16-col N-tiles. A-fragments (cell_tau hi/lo bf16, truncation split)
// are computed directly in registers -> no LDS staging, no barriers in the
// r-loop. Wave 3 additionally handles the log path (wave-local reduce).
// ---------------------------------------------------------------------------
__global__ __launch_bounds__(256, 3) void main_kernel(
    const float* __restrict__ emb,      // (B,P,DIN)
    const float* __restrict__ mask,     // (B,P)
    const float* __restrict__ times,    // (B,P)
    const float* __restrict__ taus_u,   // (B,P-1,1,S)
    const int* __restrict__ types,      // (B,P)
    const float* __restrict__ W_start, const float* __restrict__ b_start,
    const float* __restrict__ W_conv,  const float* __restrict__ b_conv,
    const float* __restrict__ W_dec,   const float* __restrict__ b_dec,
    const float* __restrict__ W_int,   const float* __restrict__ b_int,
    float* __restrict__ out)            // (B,2), pre-zeroed
{
  const int tid = threadIdx.x;
  const int b = blockIdx.x / NTB;
  const int t0 = (blockIdx.x % NTB) * TT;
  const int lane = tid & 63;
  const int wv = tid >> 6;
  const int rowq = lane >> 4;     // 0..3 (d-slot / C-row group)
  const int l15 = lane & 15;      // M-row within tile / N-col within tile

  __shared__ __align__(16) float s_emb[TT][DINv];
  __shared__ __align__(16) float s_st[TT][DINv];    // gelu(start)*np
  __shared__ __align__(16) float s_cv[TT][DINv];    // gelu(conv)*np
  __shared__ __align__(16) float s_nom[TT][DINv];   // -softplus10(dec)*np
  __shared__ float s_tau[TT][Sv];
  __shared__ __align__(16) short s_wthi[32 * DINv]; // W_int^T swizzled bf16 hi
  __shared__ __align__(16) short s_wtlo[32 * DINv]; // bf16 lo
  __shared__ float s_dt[TT], s_npm[TT];
  __shared__ int   s_kt[TT];
  __shared__ float s_bint[Kv];
  __shared__ float s_red[4];
  __shared__ float s_ls;

  // ---- one-time staging -------------------------------------------------
  for (int i = tid; i < 32 * DINv; i += 256) {
    int k = i >> 7, d = i & 127;
    float w = (k < Kv) ? W_int[d * Kv + k] : 0.f;
    u32 wb = __float_as_uint(w);
    short hi = (short)(wb >> 16);                       // truncation split
    float hf = __uint_as_float(wb & 0xffff0000u);
    short lo = (short)(__float_as_uint(w - hf) >> 16);
    int a = k * 128 + ((((d >> 3) ^ k) & 7) << 3) + ((d >> 6) << 6) + (d & 7);
    s_wthi[a] = hi;
    s_wtlo[a] = lo;
  }
  if (tid < Kv) s_bint[tid] = b_int[tid];

  for (int i = tid; i < TT * DINv; i += 256) {
    int r = i >> 7, d = i & 127;
    int t = t0 + r;
    s_emb[r][d] = (t < Pv - 1) ? emb[(b * Pv + t) * DINv + d] : 0.f;
  }
  for (int i = tid; i < TT * Sv; i += 256) {
    int r = i / Sv, s = i % Sv;
    int t = t0 + r;
    s_tau[r][s] = (t < Pv - 1) ? taus_u[(b * (Pv - 1) + t) * Sv + s] : 0.f;
  }
  if (tid < TT) {
    int t = t0 + tid;
    float np = 0.f, dtv = 0.f; int kt = 0;
    if (t < Pv - 1) {
      np = mask[b * Pv + t + 1];
      dtv = (times[b * Pv + t + 1] - times[b * Pv + t]) * np;
      int ty = types[b * Pv + t + 1] - 1;
      kt = min(max(ty, 0), Kv - 1);
    }
    s_npm[tid] = np; s_dt[tid] = dtv; s_kt[tid] = kt;
  }
  __syncthreads();

  // ---- matvecs: 384 column-tasks over 256 threads -----------------------
  for (int task = tid; task < 3 * DINv; task += 256) {
    const int which = task >> 7;   // 0:start 1:conv 2:dec
    const int j = task & 127;
    const float* W = (which == 0) ? W_start : (which == 1) ? W_conv : W_dec;
    const float* bias = (which == 0) ? b_start : (which == 1) ? b_conv : b_dec;
    float acc[TT];
#pragma unroll
    for (int r = 0; r < TT; ++r) acc[r] = 0.f;
    for (int d = 0; d < DINv; ++d) {
      float w = W[d * DINv + j];
#pragma unroll
      for (int r = 0; r < TT; ++r) acc[r] = fmaf(s_emb[r][d], w, acc[r]);
    }
    float bj = bias[j];
#pragma unroll
    for (int r = 0; r < TT; ++r) {
      float v = acc[r] + bj;
      float np = s_npm[r];
      if (which == 0)      s_st[r][j]  = gelu_f(v) * np;
      else if (which == 1) s_cv[r][j]  = gelu_f(v) * np;
      else                 s_nom[r][j] = -softplus10(v) * np;
    }
  }
  __syncthreads();

  const float bk0 = s_bint[l15];                       // k0 = l15 < 20 always
  const bool  k1ok = (l15 < Kv - 16);                  // k1 = 16+l15 valid
  const float bk1 = k1ok ? s_bint[16 + l15] : 0.f;

  float integ = 0.f;
  float logsum = 0.f;
  const int nr = min(TT, (Pv - 1) - t0);
  const int mtA = wv;          // always valid (0..3)
  const int mtB = wv + 4;      // valid if < 7

// Build A-fragment (8 d's) in registers and run the 6 hi/lo MFMAs for one
// (mt, ks). Fragment mapping identical to the round-6 verified kernel:
// A row = mt*16+l15, d = (ks*4+rowq)*8 + j;  B col = l15 (+16), same d map.
#define BUILD_AND_MMA(MT, ACC0, ACC1)                                          \
  {                                                                            \
    int sr = (MT) * 16 + l15; if (sr > Sv - 1) sr = Sv - 1;                    \
    const float p = dtv * s_tau[r][sr];                                        \
    _Pragma("unroll")                                                          \
    for (int ks = 0; ks < 4; ++ks) {                                           \
      const int ub = (ks * 4 + rowq) << 3;                                     \
      f32x4 cvA = *(const f32x4*)&s_cv[r][ub];                                 \
      f32x4 cvB = *(const f32x4*)&s_cv[r][ub + 4];                             \
      f32x4 stA = *(const f32x4*)&s_st[r][ub];                                 \
      f32x4 stB = *(const f32x4*)&s_st[r][ub + 4];                             \
      f32x4 nmA = *(const f32x4*)&s_nom[r][ub];                                \
      f32x4 nmB = *(const f32x4*)&s_nom[r][ub + 4];                            \
      float ct[8];                                                             \
      _Pragma("unroll")                                                        \
      for (int j = 0; j < 4; ++j) {                                            \
        float e0 = __expf(nmA[j] * p);                                         \
        float x0 = fmaf(stA[j] - cvA[j], e0, cvA[j]);                          \
        float q0 = __expf(2.0f * x0);                                          \
        ct[j] = 1.0f - __fdividef(2.0f, q0 + 1.0f);                            \
        float e1 = __expf(nmB[j] * p);                                         \
        float x1 = fmaf(stB[j] - cvB[j], e1, cvB[j]);                          \
        float q1 = __expf(2.0f * x1);                                          \
        ct[j + 4] = 1.0f - __fdividef(2.0f, q1 + 1.0f);                        \
      }                                                                        \
      u32x4 hv, lv;                                                            \
      _Pragma("unroll")                                                        \
      for (int q = 0; q < 4; ++q) {                                            \
        u32 b0 = __float_as_uint(ct[2 * q]);                                   \
        u32 b1 = __float_as_uint(ct[2 * q + 1]);                               \
        hv[q] = (b0 >> 16) | (b1 & 0xffff0000u);                               \
        float f0 = ct[2 * q]     - __uint_as_float(b0 & 0xffff0000u);          \
        float f1 = ct[2 * q + 1] - __uint_as_float(b1 & 0xffff0000u);          \
        lv[q] = (__float_as_uint(f0) >> 16) | (__float_as_uint(f1) & 0xffff0000u); \
      }                                                                        \
      bf16x8 ah = __builtin_bit_cast(bf16x8, hv);                              \
      bf16x8 al = __builtin_bit_cast(bf16x8, lv);                              \
      const int ba0 = l15 * 128 + ((((ub >> 3) ^ l15) & 7) << 3) + ((ub >> 6) << 6); \
      bf16x8 bh0 = *(const bf16x8*)&s_wthi[ba0];                               \
      bf16x8 bl0 = *(const bf16x8*)&s_wtlo[ba0];                               \
      bf16x8 bh1 = *(const bf16x8*)&s_wthi[ba0 + 2048];                        \
      bf16x8 bl1 = *(const bf16x8*)&s_wtlo[ba0 + 2048];                        \
      ACC0 = __builtin_amdgcn_mfma_f32_16x16x32_bf16(ah, bh0, ACC0, 0, 0, 0);  \
      ACC0 = __builtin_amdgcn_mfma_f32_16x16x32_bf16(al, bh0, ACC0, 0, 0, 0);  \
      ACC0 = __builtin_amdgcn_mfma_f32_16x16x32_bf16(ah, bl0, ACC0, 0, 0, 0);  \
      ACC1 = __builtin_amdgcn_mfma_f32_16x16x32_bf16(ah, bh1, ACC1, 0, 0, 0);  \
      ACC1 = __builtin_amdgcn_mfma_f32_16x16x32_bf16(al, bh1, ACC1, 0, 0, 0);  \
      ACC1 = __builtin_amdgcn_mfma_f32_16x16x32_bf16(ah, bl1, ACC1, 0, 0, 0);  \
    }                                                                          \
  }

// C layout (verified): col = l15, row = rowq*4 + jj.
#define EPILOGUE(MT, ACC0, ACC1)                                               \
  {                                                                            \
    float ps = 0.f;                                                            \
    _Pragma("unroll")                                                          \
    for (int jj = 0; jj < 4; ++jj) {                                           \
      int s = (MT) * 16 + rowq * 4 + jj;                                       \
      if (s < Sv) {                                                            \
        ps += softplus1(ACC0[jj] + bk0);                                       \
        if (k1ok) ps += softplus1(ACC1[jj] + bk1);                             \
      }                                                                        \
    }                                                                          \
    integ += dtv * ps;                                                         \
  }

  for (int r = 0; r < nr; ++r) {
    const float dtv = s_dt[r];

    // ---- log path: wave 3 only, wave-local (no barrier)
    if (wv == 3) {
      float pl = 0.f;
#pragma unroll
      for (int h = 0; h < 2; ++h) {
        int d = lane + 64 * h;
        float cv = s_cv[r][d];
        float e = __expf(s_nom[r][d] * dtv);
        float x = fmaf(s_st[r][d] - cv, e, cv);
        pl = fmaf(fast_tanh(x), W_int[d * Kv + s_kt[r]], pl);
      }
#pragma unroll
      for (int o = 32; o > 0; o >>= 1) pl += __shfl_xor(pl, o);
      if (lane == 0 && s_npm[r] > 0.f)
        logsum += logf(softplus1(pl + s_bint[s_kt[r]]));
    }

    f32x4 z = {0.f, 0.f, 0.f, 0.f};
    f32x4 aA0 = z, aA1 = z, aB0 = z, aB1 = z;
    BUILD_AND_MMA(mtA, aA0, aA1);
    if (mtB < 7) BUILD_AND_MMA(mtB, aB0, aB1);
    EPILOGUE(mtA, aA0, aA1);
    if (mtB < 7) EPILOGUE(mtB, aB0, aB1);
  }

  // ---- single end-of-block reduce ---------------------------------------
#pragma unroll
  for (int o = 32; o > 0; o >>= 1) integ += __shfl_xor(integ, o);
  if (lane == 0) s_red[wv] = integ;
  if (wv == 3 && lane == 0) s_ls = logsum;
  __syncthreads();
  if (tid == 0) {
    atomicAdd(&out[b * 2 + 0], s_ls);
    atomicAdd(&out[b * 2 + 1],
              (s_red[0] + s_red[1] + s_red[2] + s_red[3]) * (1.0f / Sv));
  }
}

extern "C" void kernel_launch(void* const* d_in, const int* in_sizes, int n_in,
                              void* d_out, int out_size, void* d_ws, size_t ws_size,
                              hipStream_t stream) {
  const float* values  = (const float*)d_in[0];
  const float* pre     = (const float*)d_in[1];
  const float* mask    = (const float*)d_in[2];
  const float* times   = (const float*)d_in[3];
  const float* tausu   = (const float*)d_in[4];
  const int*   types   = (const int*)d_in[5];
  const float* W_start = (const float*)d_in[6];
  const float* b_start = (const float*)d_in[7];
  const float* W_conv  = (const float*)d_in[8];
  const float* b_conv  = (const float*)d_in[9];
  const float* W_dec   = (const float*)d_in[10];
  const float* b_dec   = (const float*)d_in[11];
  const float* W_int   = (const float*)d_in[12];
  const float* b_int   = (const float*)d_in[13];
  float* out = (float*)d_out;
  float* emb = (float*)d_ws;   // B*P*DIN floats = 3.1 MB

  (void)hipMemsetAsync(out, 0, out_size * sizeof(float), stream);
  attn_kernel<<<dim3(Bv * Mv * NCH), dim3(256), 0, stream>>>(values, pre, mask, emb);
  main_kernel<<<dim3(Bv * NTB), dim3(256), 0, stream>>>(
      emb, mask, times, tausu, types,
      W_start, b_start, W_conv, b_conv, W_dec, b_dec, W_int, b_int, out);
}